// Round 5
// baseline (130.274 us; speedup 1.0000x reference)
//
#include <hip/hip_runtime.h>

#define B_ROWS 8192
#define IN_DIM 2048
#define D_DIM  1024
#define C_CLS  1000

typedef __attribute__((ext_vector_type(8))) short   bf16x8;
typedef __attribute__((ext_vector_type(4))) float   f32x4;

__device__ __forceinline__ unsigned short f2b(float f) {
    unsigned int u = __builtin_bit_cast(unsigned int, f);
    u = u + 0x7fffu + ((u >> 16) & 1u);   // RNE
    return (unsigned short)(u >> 16);
}
__device__ __forceinline__ unsigned cvtpk(float lo, float hi) {
    unsigned r;
    asm("v_cvt_pk_bf16_f32 %0, %1, %2" : "=v"(r) : "v"(lo), "v"(hi));
    return r;
}
__device__ __forceinline__ void g2lds16(const void* g, void* l) {
    __builtin_amdgcn_global_load_lds(
        (const __attribute__((address_space(1))) unsigned int*)g,
        (__attribute__((address_space(3))) unsigned int*)l,
        16, 0, 0);
}

// ---------------- fused prep: W transpose+convert (blocks 0..2047), proto convert+p2 (2048..3071)
__global__ __launch_bounds__(256) void k_pre(const float* __restrict__ W,
                                             const float* __restrict__ P,
                                             unsigned short* __restrict__ Wt,
                                             unsigned short* __restrict__ Pb,
                                             float* __restrict__ p2) {
    const int tid = threadIdx.x;
    if (blockIdx.x < 2048) {
        __shared__ float t[32][33];
        const int tx = tid & 31, ty = tid >> 5;           // 32 x 8
        const int kb = (blockIdx.x & 63) * 32;            // K (2048/32=64)
        const int nb = (blockIdx.x >> 6) * 32;            // N (1024/32=32)
#pragma unroll
        for (int j = 0; j < 4; ++j)
            t[ty + 8 * j][tx] = W[(size_t)(kb + ty + 8 * j) * D_DIM + nb + tx];
        __syncthreads();
#pragma unroll
        for (int j = 0; j < 4; ++j)
            Wt[(size_t)(nb + ty + 8 * j) * IN_DIM + kb + tx] = f2b(t[tx][ty + 8 * j]);
    } else {
        const int c = blockIdx.x - 2048;   // 0..1023
        float s = 0.f;
        if (c < C_CLS) {
            float4 v = *((const float4*)(P + (size_t)c * D_DIM) + tid);
            s = v.x * v.x + v.y * v.y + v.z * v.z + v.w * v.w;
            ushort4 h; h.x = f2b(v.x); h.y = f2b(v.y); h.z = f2b(v.z); h.w = f2b(v.w);
            *((ushort4*)(Pb + (size_t)c * D_DIM) + tid) = h;
        } else {
            ushort4 h; h.x = 0; h.y = 0; h.z = 0; h.w = 0;
            *((ushort4*)(Pb + (size_t)c * D_DIM) + tid) = h;
        }
#pragma unroll
        for (int o = 32; o > 0; o >>= 1) s += __shfl_down(s, o);
        __shared__ float red[4];
        if ((tid & 63) == 0) red[tid >> 6] = s;
        __syncthreads();
        if (tid == 0) p2[c] = red[0] + red[1] + red[2] + red[3];
    }
}

// ---------------- deep-pipelined GEMM: tile 256x128, BK=64, 512 thr (8 waves 4Mx2N)
// One {lgkmcnt/vmcnt; barrier} per K-tile; counted vmcnt via load-dependency FIFO.
// MODE 0: Zb = cvt_bf16(x) @ Wt^T + bias + z2 partials.
//         A reg-staged ONE TILE AHEAD: WRITEA(t+1) in tile t consumes loads from
//         tile t-1 (latency hidden); its implicit vmcnt(2) also guarantees B(t+1).
//         A: 2 LDS buffers, B: 3 buffers.
// MODE 1: Out = (2*(Zb @ Pb^T) - z2 - p2)/1024; both operands async 2-ahead, vmcnt(6).
template <int MODE>
__global__ __launch_bounds__(512, 2) void k_gemm8(
    const float* __restrict__ Axf,            // MODE0: x f32 [8192][2048]
    const unsigned short* __restrict__ Ab,    // MODE1: Zb [8192][1024]
    const unsigned short* __restrict__ Bt,    // [N][K] bf16
    const float* __restrict__ bias,
    const float* __restrict__ z2p_in,         // MODE1: [16][8192]
    const float* __restrict__ p2,
    unsigned short* __restrict__ Zout,
    float* __restrict__ z2p_out,
    float* __restrict__ Out) {
    constexpr int K  = (MODE == 0) ? IN_DIM : D_DIM;
    constexpr int NT = K / 64;
    constexpr unsigned ASZ = 256 * 64 * 2;    // 32 KB / stage
    constexpr unsigned BSZ = 128 * 64 * 2;    // 16 KB / stage
    constexpr int NA = (MODE == 0) ? 2 : 3;
    extern __shared__ char lds[];
    char* pa0 = lds;                 char* pa1 = lds + ASZ;
    char* pa2 = (MODE == 0) ? pa1 : lds + 2 * ASZ;        // MODE1 only
    char* pb0 = lds + NA * ASZ;      char* pb1 = pb0 + BSZ;  char* pb2 = pb0 + 2 * BSZ;
    float* z2loc = (float*)(lds + NA * ASZ + 3 * BSZ);    // 1 KB (MODE1)

    const int tid  = threadIdx.x;
    const int wave = tid >> 6, lane = tid & 63;
    const int lo = lane & 15, hi = lane >> 4;
    const int wm = wave >> 1, wn = wave & 1;   // 4M x 2N waves, 64x64 each

    const int swz = ((blockIdx.x & 7) << 5) + (blockIdx.x >> 3);
    const int bm = swz >> 3, bn = swz & 7;     // 32 x 8
    const int rowbase = bm * 256, colbase = bn * 128;

    const int srow   = lane >> 3;
    const int gchunk = (lane & 7) ^ (srow & 7);

    auto STAGE_B = [&](char* dst, int kt, int i) {   // i 0..1
        const int s = i * 8 + wave;
        g2lds16(Bt + (size_t)(colbase + s * 8 + srow) * K + kt * 64 + gchunk * 8,
                dst + s * 1024);
    };
    auto STAGE_A_ASY = [&](char* dst, int kt, int i) {  // i 0..3 (MODE1)
        const int s = i * 8 + wave;
        g2lds16(Ab + (size_t)(rowbase + s * 8 + srow) * K + kt * 64 + gchunk * 8,
                dst + s * 1024);
    };

    // MODE0 A reg-stage: thread -> row tid>>1, half tid&1 (32 f32 = 128B)
    const int arow  = tid >> 1;
    const int ahalf = tid & 1;
    float4 areg[8];
    auto LOADA = [&](int kt) {
        const float4* gp =
            (const float4*)(Axf + (size_t)(rowbase + arow) * K + kt * 64 + ahalf * 32);
#pragma unroll
        for (int i = 0; i < 8; ++i) areg[i] = gp[i];
    };
    auto WRITEA = [&](char* dst) {
#pragma unroll
        for (int j = 0; j < 4; ++j) {
            uint4 w;
            w.x = cvtpk(areg[2 * j].x,     areg[2 * j].y);
            w.y = cvtpk(areg[2 * j].z,     areg[2 * j].w);
            w.z = cvtpk(areg[2 * j + 1].x, areg[2 * j + 1].y);
            w.w = cvtpk(areg[2 * j + 1].z, areg[2 * j + 1].w);
            const int c = ahalf * 4 + j;
            *(uint4*)(dst + arow * 128 + ((c ^ (arow & 7)) << 4)) = w;
        }
    };

    f32x4 acc[4][4];
#pragma unroll
    for (int m = 0; m < 4; ++m)
#pragma unroll
        for (int n = 0; n < 4; ++n) acc[m][n] = (f32x4){0.f, 0.f, 0.f, 0.f};

    // ---- prologue
    if constexpr (MODE == 0) {
        LOADA(0);                                   // A(0) x8   (oldest)
        STAGE_B(pb0, 0, 0); STAGE_B(pb0, 0, 1);     // B(0) x2
        STAGE_B(pb1, 1, 0); STAGE_B(pb1, 1, 1);     // B(1) x2
        WRITEA(pa0);                                // implicit vmcnt(4): A(0) done
        LOADA(1);                                   // A(1) x8 -> areg
        // B(0) must land; leave B(1)x2 + A(1)x8 in flight
        asm volatile("s_waitcnt vmcnt(10) lgkmcnt(0)" ::: "memory");
    } else {
        if (tid < 256) {
            float s = 0.f;
#pragma unroll
            for (int j = 0; j < 16; ++j) s += z2p_in[j * B_ROWS + rowbase + tid];
            z2loc[tid] = s;
        }
#pragma unroll
        for (int i = 0; i < 4; ++i) STAGE_A_ASY(pa0, 0, i);
        STAGE_B(pb0, 0, 0); STAGE_B(pb0, 0, 1);
#pragma unroll
        for (int i = 0; i < 4; ++i) STAGE_A_ASY(pa1, 1, i);
        STAGE_B(pb1, 1, 0); STAGE_B(pb1, 1, 1);
        asm volatile("s_waitcnt vmcnt(6) lgkmcnt(0)" ::: "memory");
    }
    __builtin_amdgcn_s_barrier();

    auto COMPUTE = [&]() {
#pragma unroll
        for (int ks = 0; ks < 2; ++ks) {
            bf16x8 af[4], bfr[4];
#pragma unroll
            for (int m = 0; m < 4; ++m) {
                const int row = wm * 64 + m * 16 + lo;
                unsigned addr = (unsigned)(row * 128 + ks * 64 + hi * 16)
                              ^ (unsigned)((lo & 7) << 4);
                af[m] = *(const bf16x8*)(pa0 + addr);
            }
#pragma unroll
            for (int n = 0; n < 4; ++n) {
                const int row = wn * 64 + n * 16 + lo;
                unsigned addr = (unsigned)(row * 128 + ks * 64 + hi * 16)
                              ^ (unsigned)((lo & 7) << 4);
                bfr[n] = *(const bf16x8*)(pb0 + addr);
            }
            __builtin_amdgcn_s_setprio(1);
#pragma unroll
            for (int m = 0; m < 4; ++m)
#pragma unroll
                for (int n = 0; n < 4; ++n)
                    acc[m][n] = __builtin_amdgcn_mfma_f32_16x16x32_bf16(
                        af[m], bfr[n], acc[m][n], 0, 0, 0);
            __builtin_amdgcn_s_setprio(0);
        }
    };
    auto ROTATE_B = [&]() { char* t = pb0; pb0 = pb1; pb1 = pb2; pb2 = t; };

    // ---- main loop
    for (int t = 0; t < NT; ++t) {
        const bool stg = (t < NT - 2);
        if (stg) {
            if constexpr (MODE == 1) {
#pragma unroll
                for (int i = 0; i < 4; ++i) STAGE_A_ASY(pa2, t + 2, i);
            }
            STAGE_B(pb2, t + 2, 0); STAGE_B(pb2, t + 2, 1);
        }
        COMPUTE();
        if (t < NT - 1) {
            if constexpr (MODE == 0) {
                WRITEA(pa1);             // implicit counted vmcnt: A(t+1) done => B(t+1) done
                if (stg) LOADA(t + 2);   // next tile's A, full tile of latency ahead
                asm volatile("s_waitcnt lgkmcnt(0)" ::: "memory");
            } else {
                if (stg) asm volatile("s_waitcnt vmcnt(6)" ::: "memory");
                else     asm volatile("s_waitcnt vmcnt(0)" ::: "memory");
            }
            __builtin_amdgcn_s_barrier();
            if constexpr (MODE == 0) { char* t2 = pa0; pa0 = pa1; pa1 = t2; }
            else                     { char* t2 = pa0; pa0 = pa1; pa1 = pa2; pa2 = t2; }
            ROTATE_B();
        }
    }

    // ---- epilogue (C/D: col = lane&15, row = (lane>>4)*4 + reg)
    if constexpr (MODE == 0) {
        float bv[4];
#pragma unroll
        for (int n = 0; n < 4; ++n) bv[n] = bias[colbase + wn * 64 + n * 16 + lo];
#pragma unroll
        for (int m = 0; m < 4; ++m)
#pragma unroll
            for (int r = 0; r < 4; ++r) {
                const int rg = rowbase + wm * 64 + m * 16 + hi * 4 + r;
                float s = 0.f;
#pragma unroll
                for (int n = 0; n < 4; ++n) {
                    const float zf = acc[m][n][r] + bv[n];
                    Zout[(size_t)rg * D_DIM + colbase + wn * 64 + n * 16 + lo] = f2b(zf);
                    s += zf * zf;
                }
                s += __shfl_xor(s, 1); s += __shfl_xor(s, 2);
                s += __shfl_xor(s, 4); s += __shfl_xor(s, 8);
                if (lo == 0) z2p_out[(size_t)(bn * 2 + wn) * B_ROWS + rg] = s;
            }
    } else {
        float p2v[4];
#pragma unroll
        for (int n = 0; n < 4; ++n) p2v[n] = p2[colbase + wn * 64 + n * 16 + lo];
#pragma unroll
        for (int m = 0; m < 4; ++m)
#pragma unroll
            for (int r = 0; r < 4; ++r) {
                const int rl = wm * 64 + m * 16 + hi * 4 + r;
                const int rg = rowbase + rl;
                const float zv = z2loc[rl];
#pragma unroll
                for (int n = 0; n < 4; ++n) {
                    const int cg = colbase + wn * 64 + n * 16 + lo;
                    if (cg < C_CLS)
                        Out[(size_t)rg * C_CLS + cg] =
                            (2.f * acc[m][n][r] - zv - p2v[n]) * (1.f / 1024.f);
                }
            }
    }
}

extern "C" void kernel_launch(void* const* d_in, const int* in_sizes, int n_in,
                              void* d_out, int out_size, void* d_ws, size_t ws_size,
                              hipStream_t stream) {
    const float* x = (const float*)d_in[0];   // [8192, 2048]
    const float* W = (const float*)d_in[1];   // [2048, 1024]
    const float* b = (const float*)d_in[2];   // [1024]
    const float* P = (const float*)d_in[3];   // [1000, 1024]
    float* out = (float*)d_out;               // [8192, 1000]

    char* ws = (char*)d_ws;
    unsigned short* Wt  = (unsigned short*)(ws);                        //  4 MB
    unsigned short* Pb  = (unsigned short*)(ws + (4  << 20));           //  2 MB
    unsigned short* Zb  = (unsigned short*)(ws + (6  << 20));           // 16 MB
    float*          p2  = (float*)(ws + (22 << 20) + (64 << 10));       //  4 KB
    float*          z2p = (float*)(ws + (22 << 20) + (128 << 10));      // 512 KB

    const unsigned lds0 = 2 * (256 * 64 * 2) + 3 * (128 * 64 * 2);          // 112 KB
    const unsigned lds1 = 3 * (256 * 64 * 2) + 3 * (128 * 64 * 2) + 1024;   // 145 KB

    k_pre<<<dim3(3072), dim3(256), 0, stream>>>(W, P, Wt, Pb, p2);
    k_gemm8<0><<<dim3(256), dim3(512), lds0, stream>>>(
        x, nullptr, Wt, b, nullptr, nullptr, Zb, z2p, nullptr);
    k_gemm8<1><<<dim3(256), dim3(512), lds1, stream>>>(
        nullptr, Zb, Pb, nullptr, z2p, p2, nullptr, nullptr, out);
}

// Round 6
// 80.534 us; speedup vs baseline: 1.6176x; 1.6176x over previous
//
#include <hip/hip_runtime.h>

#define B_ROWS 8192
#define IN_DIM 2048
#define D_DIM  1024
#define C_CLS  1000

typedef __attribute__((ext_vector_type(8))) short   bf16x8;
typedef __attribute__((ext_vector_type(4))) float   f32x4;

__device__ __forceinline__ unsigned short f2b(float f) {
    unsigned int u = __builtin_bit_cast(unsigned int, f);
    u = u + 0x7fffu + ((u >> 16) & 1u);   // RNE
    return (unsigned short)(u >> 16);
}
__device__ __forceinline__ void g2lds16(const void* g, void* l) {
    __builtin_amdgcn_global_load_lds(
        (const __attribute__((address_space(1))) unsigned int*)g,
        (__attribute__((address_space(3))) unsigned int*)l,
        16, 0, 0);
}

// ---------------- fused prep, one launch:
//   blocks [0,2048):      W[2048][1024] f32 -> Wt[1024][2048] bf16 (transpose+cvt)
//   blocks [2048,3072):   prototypes -> Pb bf16 (rows >=1000 zeroed) + p2
//   blocks [3072,11264):  x f32 -> xb bf16 (8 elems/thread)
__global__ __launch_bounds__(256) void k_pre(const float* __restrict__ W,
                                             const float* __restrict__ P,
                                             const float* __restrict__ x,
                                             unsigned short* __restrict__ Wt,
                                             unsigned short* __restrict__ Pb,
                                             unsigned short* __restrict__ xb,
                                             float* __restrict__ p2) {
    const int tid = threadIdx.x;
    if (blockIdx.x >= 3072) {
        const size_t i = (((size_t)blockIdx.x - 3072) * 256 + tid) * 8;
        float4 v0 = *(const float4*)(x + i);
        float4 v1 = *(const float4*)(x + i + 4);
        bf16x8 h;
        h[0] = (short)f2b(v0.x); h[1] = (short)f2b(v0.y);
        h[2] = (short)f2b(v0.z); h[3] = (short)f2b(v0.w);
        h[4] = (short)f2b(v1.x); h[5] = (short)f2b(v1.y);
        h[6] = (short)f2b(v1.z); h[7] = (short)f2b(v1.w);
        *(bf16x8*)(xb + i) = h;
    } else if (blockIdx.x < 2048) {
        __shared__ float t[32][33];
        const int tx = tid & 31, ty = tid >> 5;           // 32 x 8
        const int kb = (blockIdx.x & 63) * 32;            // K (2048/32=64)
        const int nb = (blockIdx.x >> 6) * 32;            // N (1024/32=32)
#pragma unroll
        for (int j = 0; j < 4; ++j)
            t[ty + 8 * j][tx] = W[(size_t)(kb + ty + 8 * j) * D_DIM + nb + tx];
        __syncthreads();
#pragma unroll
        for (int j = 0; j < 4; ++j)
            Wt[(size_t)(nb + ty + 8 * j) * IN_DIM + kb + tx] = f2b(t[tx][ty + 8 * j]);
    } else {
        const int c = blockIdx.x - 2048;   // 0..1023
        float s = 0.f;
        if (c < C_CLS) {
            float4 v = *((const float4*)(P + (size_t)c * D_DIM) + tid);
            s = v.x * v.x + v.y * v.y + v.z * v.z + v.w * v.w;
            ushort4 h; h.x = f2b(v.x); h.y = f2b(v.y); h.z = f2b(v.z); h.w = f2b(v.w);
            *((ushort4*)(Pb + (size_t)c * D_DIM) + tid) = h;
        } else {
            ushort4 h; h.x = 0; h.y = 0; h.z = 0; h.w = 0;
            *((ushort4*)(Pb + (size_t)c * D_DIM) + tid) = h;
        }
#pragma unroll
        for (int o = 32; o > 0; o >>= 1) s += __shfl_down(s, o);
        __shared__ float red[4];
        if ((tid & 63) == 0) red[tid >> 6] = s;
        __syncthreads();
        if (tid == 0) p2[c] = red[0] + red[1] + red[2] + red[3];
    }
}

// ---------------- deep-pipelined GEMM: tile 256x128, BK=64, 512 thr (8 waves 4Mx2N)
// Fully async both operands (global_load_lds), 3-stage LDS, ONE {vmcnt(6); barrier}
// per K-tile (the MODE-1-validated structure from round 5).
// MODE 0: Zb = xb @ Wt^T + bias (bf16 out) + z2 partials.   K = 2048
// MODE 1: Out = (2*(Zb @ Pb^T) - z2 - p2)/1024.             K = 1024
template <int MODE>
__global__ __launch_bounds__(512, 2) void k_gemm8(
    const unsigned short* __restrict__ Ab,    // [M][K] bf16
    const unsigned short* __restrict__ Bt,    // [N][K] bf16
    const float* __restrict__ bias,
    const float* __restrict__ z2p_in,         // MODE1: [16][8192]
    const float* __restrict__ p2,
    unsigned short* __restrict__ Zout,
    float* __restrict__ z2p_out,
    float* __restrict__ Out) {
    constexpr int K  = (MODE == 0) ? IN_DIM : D_DIM;
    constexpr int NT = K / 64;
    constexpr unsigned ASZ = 256 * 64 * 2;    // 32 KB / stage
    constexpr unsigned BSZ = 128 * 64 * 2;    // 16 KB / stage
    extern __shared__ char lds[];
    char* pa0 = lds;            char* pa1 = lds + ASZ;  char* pa2 = lds + 2 * ASZ;
    char* pb0 = lds + 3 * ASZ;  char* pb1 = pb0 + BSZ;  char* pb2 = pb0 + 2 * BSZ;
    float* z2loc = (float*)(lds + 3 * (ASZ + BSZ));     // 1 KB (MODE1)

    const int tid  = threadIdx.x;
    const int wave = tid >> 6, lane = tid & 63;
    const int lo = lane & 15, hi = lane >> 4;
    const int wm = wave >> 1, wn = wave & 1;   // 4M x 2N waves, 64x64 each

    // XCD-aware bijective swizzle: XCD c owns bm in [4c, 4c+4) x all bn
    const int swz = ((blockIdx.x & 7) << 5) + (blockIdx.x >> 3);
    const int bm = swz >> 3, bn = swz & 7;     // 32 x 8
    const int rowbase = bm * 256, colbase = bn * 128;

    const int srow   = lane >> 3;
    const int gchunk = (lane & 7) ^ (srow & 7);   // pre-XOR'd source, linear LDS dest

    auto STAGE_A = [&](char* dst, int kt, int i) {   // i 0..3 (32 segs / 8 waves)
        const int s = i * 8 + wave;
        g2lds16(Ab + (size_t)(rowbase + s * 8 + srow) * K + kt * 64 + gchunk * 8,
                dst + s * 1024);
    };
    auto STAGE_B = [&](char* dst, int kt, int i) {   // i 0..1 (16 segs / 8 waves)
        const int s = i * 8 + wave;
        g2lds16(Bt + (size_t)(colbase + s * 8 + srow) * K + kt * 64 + gchunk * 8,
                dst + s * 1024);
    };

    f32x4 acc[4][4];
#pragma unroll
    for (int m = 0; m < 4; ++m)
#pragma unroll
        for (int n = 0; n < 4; ++n) acc[m][n] = (f32x4){0.f, 0.f, 0.f, 0.f};

    // ---- prologue: z2 partial reduce (MODE1), stage tiles 0+1, wait tile 0
    if constexpr (MODE == 1) {
        if (tid < 256) {
            float s = 0.f;
#pragma unroll
            for (int j = 0; j < 16; ++j) s += z2p_in[j * B_ROWS + rowbase + tid];
            z2loc[tid] = s;
        }
    }
#pragma unroll
    for (int i = 0; i < 4; ++i) STAGE_A(pa0, 0, i);
    STAGE_B(pb0, 0, 0); STAGE_B(pb0, 0, 1);
#pragma unroll
    for (int i = 0; i < 4; ++i) STAGE_A(pa1, 1, i);
    STAGE_B(pb1, 1, 0); STAGE_B(pb1, 1, 1);
    asm volatile("s_waitcnt vmcnt(6) lgkmcnt(0)" ::: "memory");
    __builtin_amdgcn_s_barrier();

    auto COMPUTE = [&]() {
#pragma unroll
        for (int ks = 0; ks < 2; ++ks) {
            bf16x8 af[4], bfr[4];
#pragma unroll
            for (int m = 0; m < 4; ++m) {
                const int row = wm * 64 + m * 16 + lo;
                unsigned addr = (unsigned)(row * 128 + ks * 64 + hi * 16)
                              ^ (unsigned)((lo & 7) << 4);
                af[m] = *(const bf16x8*)(pa0 + addr);
            }
#pragma unroll
            for (int n = 0; n < 4; ++n) {
                const int row = wn * 64 + n * 16 + lo;
                unsigned addr = (unsigned)(row * 128 + ks * 64 + hi * 16)
                              ^ (unsigned)((lo & 7) << 4);
                bfr[n] = *(const bf16x8*)(pb0 + addr);
            }
            __builtin_amdgcn_s_setprio(1);
#pragma unroll
            for (int m = 0; m < 4; ++m)
#pragma unroll
                for (int n = 0; n < 4; ++n)
                    acc[m][n] = __builtin_amdgcn_mfma_f32_16x16x32_bf16(
                        af[m], bfr[n], acc[m][n], 0, 0, 0);
            __builtin_amdgcn_s_setprio(0);
        }
    };

    // ---- main loop: ONE {counted vmcnt; barrier} per K-tile
    for (int t = 0; t < NT; ++t) {
        const bool stg = (t < NT - 2);
        if (stg) {
#pragma unroll
            for (int i = 0; i < 4; ++i) STAGE_A(pa2, t + 2, i);
            STAGE_B(pb2, t + 2, 0); STAGE_B(pb2, t + 2, 1);
        }
        COMPUTE();
        if (t < NT - 1) {
            if (stg) asm volatile("s_waitcnt vmcnt(6)" ::: "memory");
            else     asm volatile("s_waitcnt vmcnt(0)" ::: "memory");
            __builtin_amdgcn_s_barrier();
            char* ta = pa0; pa0 = pa1; pa1 = pa2; pa2 = ta;
            char* tb = pb0; pb0 = pb1; pb1 = pb2; pb2 = tb;
        }
    }

    // ---- epilogue (C/D: col = lane&15, row = (lane>>4)*4 + reg)
    if constexpr (MODE == 0) {
        float bv[4];
#pragma unroll
        for (int n = 0; n < 4; ++n) bv[n] = bias[colbase + wn * 64 + n * 16 + lo];
#pragma unroll
        for (int m = 0; m < 4; ++m)
#pragma unroll
            for (int r = 0; r < 4; ++r) {
                const int rg = rowbase + wm * 64 + m * 16 + hi * 4 + r;
                float s = 0.f;
#pragma unroll
                for (int n = 0; n < 4; ++n) {
                    const float zf = acc[m][n][r] + bv[n];
                    Zout[(size_t)rg * D_DIM + colbase + wn * 64 + n * 16 + lo] = f2b(zf);
                    s += zf * zf;
                }
                s += __shfl_xor(s, 1); s += __shfl_xor(s, 2);
                s += __shfl_xor(s, 4); s += __shfl_xor(s, 8);
                if (lo == 0) z2p_out[(size_t)(bn * 2 + wn) * B_ROWS + rg] = s;
            }
    } else {
        float p2v[4];
#pragma unroll
        for (int n = 0; n < 4; ++n) p2v[n] = p2[colbase + wn * 64 + n * 16 + lo];
#pragma unroll
        for (int m = 0; m < 4; ++m)
#pragma unroll
            for (int r = 0; r < 4; ++r) {
                const int rl = wm * 64 + m * 16 + hi * 4 + r;
                const int rg = rowbase + rl;
                const float zv = z2loc[rl];
#pragma unroll
                for (int n = 0; n < 4; ++n) {
                    const int cg = colbase + wn * 64 + n * 16 + lo;
                    if (cg < C_CLS)
                        Out[(size_t)rg * C_CLS + cg] =
                            (2.f * acc[m][n][r] - zv - p2v[n]) * (1.f / 1024.f);
                }
            }
    }
}

extern "C" void kernel_launch(void* const* d_in, const int* in_sizes, int n_in,
                              void* d_out, int out_size, void* d_ws, size_t ws_size,
                              hipStream_t stream) {
    const float* x = (const float*)d_in[0];   // [8192, 2048]
    const float* W = (const float*)d_in[1];   // [2048, 1024]
    const float* b = (const float*)d_in[2];   // [1024]
    const float* P = (const float*)d_in[3];   // [1000, 1024]
    float* out = (float*)d_out;               // [8192, 1000]

    char* ws = (char*)d_ws;
    unsigned short* Wt  = (unsigned short*)(ws);                        //  4 MB
    unsigned short* Pb  = (unsigned short*)(ws + (4  << 20));           //  2 MB
    unsigned short* Zb  = (unsigned short*)(ws + (6  << 20));           // 16 MB
    float*          p2  = (float*)(ws + (22 << 20) + (64 << 10));       //  4 KB
    float*          z2p = (float*)(ws + (22 << 20) + (128 << 10));      // 512 KB
    unsigned short* xb  = (unsigned short*)(ws + (23 << 20));           // 32 MB

    const unsigned lds_bytes = 3 * (256 * 64 * 2 + 128 * 64 * 2) + 1024; // 145 KB

    k_pre<<<dim3(11264), dim3(256), 0, stream>>>(W, P, x, Wt, Pb, xb, p2);
    k_gemm8<0><<<dim3(256), dim3(512), lds_bytes, stream>>>(
        xb, Wt, b, nullptr, nullptr, Zb, z2p, nullptr);
    k_gemm8<1><<<dim3(256), dim3(512), lds_bytes, stream>>>(
        Zb, Pb, nullptr, z2p, p2, nullptr, nullptr, out);
}